// Round 3
// baseline (637.077 us; speedup 1.0000x reference)
//
#include <hip/hip_runtime.h>
#include <stdint.h>

// out[m,n] = sum_k x[m,k]*W[n,k] + sum_r y[m,r]*A[n,r],  y = x @ B^T
// M=256, N=8192, K=8192, R=16. fp32 in/out; bf16 MFMA compute (thr 0.18).
//
// R8:
//  - prep_x: 6-stage butterfly (384 ds_permute + 384 adds/wave) replaced by
//    rotate-swizzled LDS transpose (64 b32 writes + 64 b32 reads, conflict
//    free: bank = (v+t)&63 distinct across lanes) + 63 adds. ~3x less
//    DS-pipe work, ~6x fewer reduction VALU ops.
//  - split-K reduction fused into lora_gemm (reduce_k dispatch removed):
//    each block stores its part slice, __threadfence (release) + ACQ_REL
//    agent-scope ticket; the last of the 4 kz-blocks per n-tile linearly
//    reduces the 4 slices (L3-hot float4) and writes out. The 4 blocks sit
//    on 4 different XCDs -> fences mandatory (G16). Overlaps reduction with
//    remaining gemm work and removes a full-grid drain + launch.
// Carried from R7: BK=128, two-deep W prefetch ping-pong, av-before-W issue
// order. From R6: 8mx1n waves, kz<->XCD-pair affinity, frag-linear xb.

#define DM 256
#define DK 8192
#define DN 8192
#define RLORA 16

#define TN 64
#define BK 128
#define KSPLIT 4
#define KCHUNK (DK / KSPLIT)    // 2048
#define NITER (KCHUNK / BK)     // 16

typedef short bf16x8 __attribute__((ext_vector_type(8)));   // 4 VGPRs
typedef float f32x4v __attribute__((ext_vector_type(4)));

__device__ __forceinline__ unsigned short f2bf(float f) {
  unsigned u = __builtin_bit_cast(unsigned, f);
  u += 0x7FFFu + ((u >> 16) & 1u);           // RNE
  return (unsigned short)(u >> 16);
}

__device__ __forceinline__ bf16x8 pack8(float4 a, float4 b) {
  bf16x8 r;
  r[0] = (short)f2bf(a.x); r[1] = (short)f2bf(a.y);
  r[2] = (short)f2bf(a.z); r[3] = (short)f2bf(a.w);
  r[4] = (short)f2bf(b.x); r[5] = (short)f2bf(b.y);
  r[6] = (short)f2bf(b.z); r[7] = (short)f2bf(b.w);
  return r;
}

// ---------------------------------------------------------------------------
// prep_x: x -> bf16 in frag-linear chunk order, + partial y = x @ B^T.
// Chunk c = (K64*32 + s*16 + g)*64 + (oct*16 + r), 16 B, holding
// x[g*16+r][K64*64 + s*32 + oct*8 .. +8)  (A-operand layout: lane&15=m-row,
// lane>>4=k-octet).  grid (8, 64) x 256 thr.
__global__ __launch_bounds__(256) void prep_x(
    const float* __restrict__ x, const float* __restrict__ Bm,
    unsigned short* __restrict__ xb, float* __restrict__ y32) {
  const int ks = blockIdx.x;
  const int m0 = blockIdx.y * 4;
  const int t = threadIdx.x;
  const int k = ks * 1024 + t * 4;
  const int K64 = k >> 6, s = (k >> 5) & 1, oct = (k >> 3) & 3;
  const int e = k & 7;                       // 0 or 4
  float4 xv[4];
#pragma unroll
  for (int i = 0; i < 4; ++i) {
    const int m = m0 + i;
    const int g = m >> 4, r = m & 15;
    xv[i] = *(const float4*)(x + (size_t)m * DK + k);
    ushort4 h;
    h.x = f2bf(xv[i].x); h.y = f2bf(xv[i].y);
    h.z = f2bf(xv[i].z); h.w = f2bf(xv[i].w);
    const size_t chunk = (size_t)(K64 * 32 + s * 16 + g) * 64 + oct * 16 + r;
    *(ushort4*)(xb + chunk * 8 + e) = h;
  }
  float acc[4][RLORA];
#pragma unroll
  for (int r = 0; r < RLORA; ++r) {
    float4 b = *(const float4*)(Bm + (size_t)r * DK + k);
#pragma unroll
    for (int i = 0; i < 4; ++i)
      acc[i][r] = xv[i].x * b.x + xv[i].y * b.y + xv[i].z * b.z + xv[i].w * b.w;
  }
  // ---- reduction: 256 threads x 64 values -> 64 sums, via LDS transpose.
  // tr[t][(v+t)&63]: per store/load instruction bank index = (v+t)&63 is
  // distinct across 32 consecutive lanes -> conflict-free (2 lanes/bank).
  __shared__ float tr[256][64];
#pragma unroll
  for (int i = 0; i < 4; ++i)
#pragma unroll
    for (int r = 0; r < RLORA; ++r) {
      const int v = i * 16 + r;
      tr[t][(v + t) & 63] = acc[i][r];
    }
  __syncthreads();
  const int v = t & 63, q = t >> 6;          // value, row-quarter
  float sq = 0.f;
#pragma unroll
  for (int j = 0; j < 64; ++j)
    sq += tr[q * 64 + j][(v + j) & 63];      // (v + q*64 + j)&63 == (v+j)&63
  __syncthreads();
  ((float*)tr)[q * 64 + v] = sq;             // tr2[4][64]
  __syncthreads();
  if (t < 64) {
    float sum = ((float*)tr)[t] + ((float*)tr)[64 + t] +
                ((float*)tr)[128 + t] + ((float*)tr)[192 + t];
    atomicAdd(y32 + (m0 + (t >> 4)) * RLORA + (t & 15), sum);
  }
}

// ---------------------------------------------------------------------------
// Main GEMM.  grid 512 x 1 (flat), 512 thr = 8 waves, wave w owns rows
// [w*32, w*32+32) x all TN=64 cols.  kz = XCD-pair (bid&7)>>1 so each XCD
// only touches its 1 MiB xb slice (L2-resident).  Split-K reduction fused
// via last-block ticket (cnt[nblk]).
__global__ __launch_bounds__(512, 4) void lora_gemm(
    const unsigned short* __restrict__ xb,   // frag-linear bf16 x
    const float* __restrict__ W,             // [8192][8192] fp32
    const float* __restrict__ y32,           // [256][16] fp32
    const float* __restrict__ Aw,            // [8192][16] fp32
    float* __restrict__ out,                 // [256][8192] fp32
    float* __restrict__ part,                // [KSPLIT][256][8192] or null
    int* __restrict__ cnt) {                 // [128] tickets (zeroed)
  __shared__ unsigned short wsm[2][8192];    // 2 x 16 KB bf16 W-tile (64n x 128k)
  __shared__ int red_old;

  const int tid = threadIdx.x;
  const int lane = tid & 63, w = tid >> 6;   // w = m-slice 0..7
  const int qr = lane & 15, quad = lane >> 4;

  // XCD-affine decode: xcd = bid&7 (round-robin dispatch), kz fixed per
  // XCD pair, nblk bijective over 0..127 for each kz.
  const int bid = blockIdx.x;
  const int xcd = bid & 7;
  const int kz = xcd >> 1;
  const int nblk = (bid >> 3) + ((xcd & 1) << 6);
  const int n0 = nblk * TN;
  const int kb = kz * KCHUNK;

  // W staging: thread stages frags f0=2w, f1=2w+1.  Frag f holds
  // W[n0 + (f&3)*16 + qr][kb + it*128 + (f>>2)*32 + quad*8 .. +8) as bf16x8
  // at LDS offset f*1024 + lane*16 (linear, conflict-free b128 writes).
  const int f0 = w * 2, f1 = f0 + 1;
  const float* wsrc0 = W + (size_t)(n0 + (f0 & 3) * 16 + qr) * DK + kb +
                       (f0 >> 2) * 32 + quad * 8;
  const float* wsrc1 = W + (size_t)(n0 + (f1 & 3) * 16 + qr) * DK + kb +
                       (f1 >> 2) * 32 + quad * 8;
  const unsigned wdst0 = (unsigned)(f0 * 64 + lane) * 16;
  const unsigned wdst1 = wdst0 + 1024;

  // a-frag stream base: chunk (K64*32 + si*16 + g)*64 + lane, K64 = kz*32 + ...
  const bf16x8* ap = (const bf16x8*)xb + ((size_t)(kz * 32) * 32) * 64 + lane;

  f32x4v acc[2][4];
#pragma unroll
  for (int a = 0; a < 2; ++a)
#pragma unroll
    for (int b = 0; b < 4; ++b) acc[a][b] = (f32x4v){0.f, 0.f, 0.f, 0.f};

  // prologue: W(0) -> g[0] -> wsm[0];  W(1) -> g[1] (packed at it=0).
  float4 g[2][4];
  g[0][0] = *(const float4*)(wsrc0);
  g[0][1] = *(const float4*)(wsrc0 + 4);
  g[0][2] = *(const float4*)(wsrc1);
  g[0][3] = *(const float4*)(wsrc1 + 4);
  g[1][0] = *(const float4*)(wsrc0 + BK);
  g[1][1] = *(const float4*)(wsrc0 + BK + 4);
  g[1][2] = *(const float4*)(wsrc1 + BK);
  g[1][3] = *(const float4*)(wsrc1 + BK + 4);
  *(bf16x8*)((char*)wsm[0] + wdst0) = pack8(g[0][0], g[0][1]);
  *(bf16x8*)((char*)wsm[0] + wdst1) = pack8(g[0][2], g[0][3]);
  __syncthreads();

#pragma unroll 2
  for (int it = 0; it < NITER; ++it) {
    const char* wcur = (const char*)wsm[it & 1];
    // (1) av for k-slices s=0,1 (K64 = it*2): 4 coalesced 16B L2 loads
    bf16x8 av[2][2];
#pragma unroll
    for (int si = 0; si < 2; ++si)
#pragma unroll
      for (int mt = 0; mt < 2; ++mt)
        av[si][mt] =
            ap[(size_t)((it * 2) * 32 + si * 16 + w * 2 + mt) * 64];
    // (2) MFMA s=0,1 (b-frags: linear lane*16 ds_read_b128, conflict-free)
#pragma unroll
    for (int s = 0; s < 2; ++s) {
      bf16x8 b[4];
#pragma unroll
      for (int sub = 0; sub < 4; ++sub)
        b[sub] = *(const bf16x8*)(wcur + (((s * 4 + sub) * 64 + lane) * 16));
#pragma unroll
      for (int mt = 0; mt < 2; ++mt)
#pragma unroll
        for (int sub = 0; sub < 4; ++sub)
          acc[mt][sub] = __builtin_amdgcn_mfma_f32_16x16x32_bf16(
              av[s][mt], b[sub], acc[mt][sub], 0, 0, 0);
    }
    // (3) av for k-slices s=2,3 (K64 = it*2+1) -- BEFORE the W issue so the
    // MFMA vmcnt wait never chains behind the fresh HBM loads (in-order).
#pragma unroll
    for (int si = 0; si < 2; ++si)
#pragma unroll
      for (int mt = 0; mt < 2; ++mt)
        av[si][mt] =
            ap[(size_t)((it * 2 + 1) * 32 + si * 16 + w * 2 + mt) * 64];
    // (4) issue W(it+2) into g[it&1] (W(it) in there was packed at it-1)
    if (it + 2 < NITER) {
      const float* p0 = wsrc0 + (size_t)(it + 2) * BK;
      const float* p1 = wsrc1 + (size_t)(it + 2) * BK;
      g[it & 1][0] = *(const float4*)(p0);
      g[it & 1][1] = *(const float4*)(p0 + 4);
      g[it & 1][2] = *(const float4*)(p1);
      g[it & 1][3] = *(const float4*)(p1 + 4);
    }
    // (5) MFMA s=2,3
#pragma unroll
    for (int s = 2; s < 4; ++s) {
      bf16x8 b[4];
#pragma unroll
      for (int sub = 0; sub < 4; ++sub)
        b[sub] = *(const bf16x8*)(wcur + (((s * 4 + sub) * 64 + lane) * 16));
#pragma unroll
      for (int mt = 0; mt < 2; ++mt)
#pragma unroll
        for (int sub = 0; sub < 4; ++sub)
          acc[mt][sub] = __builtin_amdgcn_mfma_f32_16x16x32_bf16(
              av[s - 2][mt], b[sub], acc[mt][sub], 0, 0, 0);
    }
    // (6) pack W(it+1) from g[(it+1)&1] -- loaded a full iteration ago, so
    // the vmcnt wait here is ~0: the barrier carries no HBM latency.
    if (it + 1 < NITER) {
      char* wnxt = (char*)wsm[(it + 1) & 1];
      *(bf16x8*)(wnxt + wdst0) = pack8(g[(it + 1) & 1][0], g[(it + 1) & 1][1]);
      *(bf16x8*)(wnxt + wdst1) = pack8(g[(it + 1) & 1][2], g[(it + 1) & 1][3]);
    }
    __syncthreads();
  }

  if (kz == 0) {  // LoRA tail: one K=32 MFMA round (cols >=16 zero),
                  // y read straight from y32 fp32 (pack_y folded in).
    const float4 z = {0.f, 0.f, 0.f, 0.f};
    bf16x8 b[4];
#pragma unroll
    for (int sub = 0; sub < 4; ++sub) {
      const float* ap2 = Aw + (size_t)(n0 + sub * 16 + qr) * RLORA + quad * 8;
      float4 p0 = (quad < 2) ? *(const float4*)(ap2) : z;
      float4 p1 = (quad < 2) ? *(const float4*)(ap2 + 4) : z;
      b[sub] = pack8(p0, p1);
    }
#pragma unroll
    for (int mt = 0; mt < 2; ++mt) {
      const float* yp = y32 + (size_t)(w * 32 + mt * 16 + qr) * RLORA + quad * 8;
      float4 q0 = (quad < 2) ? *(const float4*)(yp) : z;
      float4 q1 = (quad < 2) ? *(const float4*)(yp + 4) : z;
      bf16x8 avt = pack8(q0, q1);
#pragma unroll
      for (int sub = 0; sub < 4; ++sub)
        acc[mt][sub] = __builtin_amdgcn_mfma_f32_16x16x32_bf16(
            avt, b[sub], acc[mt][sub], 0, 0, 0);
    }
  }

  // epilogue: C/D col=lane&15 (n), row=quad*4+rg (m)  [m89-verified]
  if (part) {
    float* pb = part + (size_t)kz * DM * DN;
#pragma unroll
    for (int mt = 0; mt < 2; ++mt)
#pragma unroll
      for (int sub = 0; sub < 4; ++sub) {
        float* p = pb + (size_t)(w * 32 + mt * 16 + quad * 4) * DN +
                   n0 + sub * 16 + qr;
#pragma unroll
        for (int rg = 0; rg < 4; ++rg) p[(size_t)rg * DN] = acc[mt][sub][rg];
      }
    // ---- fused split-K reduction (last-block ticket, cross-XCD) ----
    __threadfence();                          // release our part slice
    __syncthreads();
    if (tid == 0)
      red_old = __hip_atomic_fetch_add(&cnt[nblk], 1, __ATOMIC_ACQ_REL,
                                       __HIP_MEMORY_SCOPE_AGENT);
    __syncthreads();
    if (red_old == KSPLIT - 1) {
      __threadfence();                        // acquire the other 3 slices
      // tile = 256 rows x 64 cols = 4096 float4; 512 thr x 8 chunks.
#pragma unroll
      for (int c = 0; c < 8; ++c) {
        const int fidx = c * 512 + tid;
        const int row = fidx >> 4, col4 = fidx & 15;
        const size_t ad = (size_t)row * DN + n0 + col4 * 4;
        float4 s0 = *(const float4*)(part + ad);
        const float4 s1 = *(const float4*)(part + (size_t)1 * DM * DN + ad);
        const float4 s2 = *(const float4*)(part + (size_t)2 * DM * DN + ad);
        const float4 s3 = *(const float4*)(part + (size_t)3 * DM * DN + ad);
        s0.x += s1.x + s2.x + s3.x;
        s0.y += s1.y + s2.y + s3.y;
        s0.z += s1.z + s2.z + s3.z;
        s0.w += s1.w + s2.w + s3.w;
        *(float4*)(out + ad) = s0;
      }
    }
  } else {
    float* ob = out;
#pragma unroll
    for (int mt = 0; mt < 2; ++mt)
#pragma unroll
      for (int sub = 0; sub < 4; ++sub) {
        float* p = ob + (size_t)(w * 32 + mt * 16 + quad * 4) * DN +
                   n0 + sub * 16 + qr;
#pragma unroll
        for (int rg = 0; rg < 4; ++rg)
          atomicAdd(p + (size_t)rg * DN, acc[mt][sub][rg]);
      }
  }
}

// ---------------------------------------------------------------------------
extern "C" void kernel_launch(void* const* d_in, const int* in_sizes, int n_in,
                              void* d_out, int out_size, void* d_ws, size_t ws_size,
                              hipStream_t stream) {
  const float* x  = (const float*)d_in[0];   // [4,64,8192]
  const float* W  = (const float*)d_in[1];   // [8192,8192]
  const float* A  = (const float*)d_in[2];   // [8192,16]
  const float* Bm = (const float*)d_in[3];   // [16,8192]
  float* out = (float*)d_out;

  unsigned short* xb = (unsigned short*)d_ws;             // 4 MiB frag-linear
  float* y32 = (float*)((char*)d_ws + (4u << 20));        // 16 KiB
  int* cnt = (int*)((char*)y32 + 16384);                  // 512 B tickets
  size_t base_bytes = (4u << 20) + 16384 + 512;
  size_t part_bytes = (size_t)KSPLIT * DM * DN * 4;       // 32 MiB
  bool use_part = ws_size >= base_bytes + part_bytes;
  float* part = use_part ? (float*)((char*)d_ws + base_bytes) : nullptr;

  if (!use_part)
    hipMemsetAsync(d_out, 0, (size_t)out_size * sizeof(float), stream);
  hipMemsetAsync(y32, 0, DM * RLORA * sizeof(float) + 512, stream);
  prep_x<<<dim3(8, 64), 256, 0, stream>>>(x, Bm, xb, y32);
  lora_gemm<<<512, 512, 0, stream>>>(xb, W, y32, A, out, part, cnt);
}

// Round 4
// 422.650 us; speedup vs baseline: 1.5073x; 1.5073x over previous
//
#include <hip/hip_runtime.h>
#include <stdint.h>

// out[m,n] = sum_k x[m,k]*W[n,k] + sum_r y[m,r]*A[n,r],  y = x @ B^T
// M=256, N=8192, K=8192, R=16. fp32 in/out; bf16 MFMA compute (thr 0.18).
//
// R9: revert R8's fused split-K (device-scope fences = L2 writeback/inv per
// block on gfx950 -> 389us stall; reduce_k dispatch is strictly cheaper).
// Keep R8's prep_x LDS-transpose reduction. New: y32 memset + prep_x atomics
// removed -- prep_x stores per-ks partials to y32p[8][256][16] (each slot
// written once, no pre-zero), lora_gemm's LoRA tail sums the 8 slots.
// Carried from R7: BK=128, two-deep W prefetch ping-pong, av-before-W issue
// order. From R6: 8mx1n waves, kz<->XCD-pair affinity, frag-linear xb.

#define DM 256
#define DK 8192
#define DN 8192
#define RLORA 16

#define TN 64
#define BK 128
#define KSPLIT 4
#define KCHUNK (DK / KSPLIT)    // 2048
#define NITER (KCHUNK / BK)     // 16

typedef short bf16x8 __attribute__((ext_vector_type(8)));   // 4 VGPRs
typedef float f32x4v __attribute__((ext_vector_type(4)));

__device__ __forceinline__ unsigned short f2bf(float f) {
  unsigned u = __builtin_bit_cast(unsigned, f);
  u += 0x7FFFu + ((u >> 16) & 1u);           // RNE
  return (unsigned short)(u >> 16);
}

__device__ __forceinline__ bf16x8 pack8(float4 a, float4 b) {
  bf16x8 r;
  r[0] = (short)f2bf(a.x); r[1] = (short)f2bf(a.y);
  r[2] = (short)f2bf(a.z); r[3] = (short)f2bf(a.w);
  r[4] = (short)f2bf(b.x); r[5] = (short)f2bf(b.y);
  r[6] = (short)f2bf(b.z); r[7] = (short)f2bf(b.w);
  return r;
}

// ---------------------------------------------------------------------------
// prep_x: x -> bf16 in frag-linear chunk order, + partial y = x @ B^T.
// Chunk c = (K64*32 + s*16 + g)*64 + (oct*16 + r), 16 B, holding
// x[g*16+r][K64*64 + s*32 + oct*8 .. +8)  (A-operand layout: lane&15=m-row,
// lane>>4=k-octet).  grid (8, 64) x 256 thr.  Partial y sums go to
// y32p[ks][m][r] (written exactly once -> no memset, no atomics).
__global__ __launch_bounds__(256) void prep_x(
    const float* __restrict__ x, const float* __restrict__ Bm,
    unsigned short* __restrict__ xb, float* __restrict__ y32p) {
  const int ks = blockIdx.x;
  const int m0 = blockIdx.y * 4;
  const int t = threadIdx.x;
  const int k = ks * 1024 + t * 4;
  const int K64 = k >> 6, s = (k >> 5) & 1, oct = (k >> 3) & 3;
  const int e = k & 7;                       // 0 or 4
  float4 xv[4];
#pragma unroll
  for (int i = 0; i < 4; ++i) {
    const int m = m0 + i;
    const int g = m >> 4, r = m & 15;
    xv[i] = *(const float4*)(x + (size_t)m * DK + k);
    ushort4 h;
    h.x = f2bf(xv[i].x); h.y = f2bf(xv[i].y);
    h.z = f2bf(xv[i].z); h.w = f2bf(xv[i].w);
    const size_t chunk = (size_t)(K64 * 32 + s * 16 + g) * 64 + oct * 16 + r;
    *(ushort4*)(xb + chunk * 8 + e) = h;
  }
  float acc[4][RLORA];
#pragma unroll
  for (int r = 0; r < RLORA; ++r) {
    float4 b = *(const float4*)(Bm + (size_t)r * DK + k);
#pragma unroll
    for (int i = 0; i < 4; ++i)
      acc[i][r] = xv[i].x * b.x + xv[i].y * b.y + xv[i].z * b.z + xv[i].w * b.w;
  }
  // ---- reduction: 256 threads x 64 values -> 64 sums, via LDS transpose.
  // tr[t][(v+t)&63]: per store/load instruction bank index = (v+t)&63 is
  // distinct across 32 consecutive lanes -> conflict-free (2 lanes/bank).
  __shared__ float tr[256][64];
#pragma unroll
  for (int i = 0; i < 4; ++i)
#pragma unroll
    for (int r = 0; r < RLORA; ++r) {
      const int v = i * 16 + r;
      tr[t][(v + t) & 63] = acc[i][r];
    }
  __syncthreads();
  const int v = t & 63, q = t >> 6;          // value, row-quarter
  float sq = 0.f;
#pragma unroll
  for (int j = 0; j < 64; ++j)
    sq += tr[q * 64 + j][(v + j) & 63];      // (v + q*64 + j)&63 == (v+j)&63
  __syncthreads();
  ((float*)tr)[q * 64 + v] = sq;             // tr2[4][64]
  __syncthreads();
  if (t < 64) {
    float sum = ((float*)tr)[t] + ((float*)tr)[64 + t] +
                ((float*)tr)[128 + t] + ((float*)tr)[192 + t];
    // slot = ks*4096 + m*16 + r, written exactly once per launch
    y32p[(size_t)ks * (DM * RLORA) + (m0 + (t >> 4)) * RLORA + (t & 15)] = sum;
  }
}

// ---------------------------------------------------------------------------
// Main GEMM.  grid 512 x 1 (flat), 512 thr = 8 waves, wave w owns rows
// [w*32, w*32+32) x all TN=64 cols.  kz = XCD-pair (bid&7)>>1 so each XCD
// only touches its 1 MiB xb slice (L2-resident).
__global__ __launch_bounds__(512, 4) void lora_gemm(
    const unsigned short* __restrict__ xb,   // frag-linear bf16 x
    const float* __restrict__ W,             // [8192][8192] fp32
    const float* __restrict__ y32p,          // [8][256][16] fp32 partials
    const float* __restrict__ Aw,            // [8192][16] fp32
    float* __restrict__ out,                 // [256][8192] fp32
    float* __restrict__ part) {              // [KSPLIT][256][8192] or null
  __shared__ unsigned short wsm[2][8192];    // 2 x 16 KB bf16 W-tile (64n x 128k)

  const int tid = threadIdx.x;
  const int lane = tid & 63, w = tid >> 6;   // w = m-slice 0..7
  const int qr = lane & 15, quad = lane >> 4;

  // XCD-affine decode: xcd = bid&7 (round-robin dispatch), kz fixed per
  // XCD pair, nblk bijective over 0..127 for each kz.
  const int bid = blockIdx.x;
  const int xcd = bid & 7;
  const int kz = xcd >> 1;
  const int nblk = (bid >> 3) + ((xcd & 1) << 6);
  const int n0 = nblk * TN;
  const int kb = kz * KCHUNK;

  // W staging: thread stages frags f0=2w, f1=2w+1.  Frag f holds
  // W[n0 + (f&3)*16 + qr][kb + it*128 + (f>>2)*32 + quad*8 .. +8) as bf16x8
  // at LDS offset f*1024 + lane*16 (linear, conflict-free b128 writes).
  const int f0 = w * 2, f1 = f0 + 1;
  const float* wsrc0 = W + (size_t)(n0 + (f0 & 3) * 16 + qr) * DK + kb +
                       (f0 >> 2) * 32 + quad * 8;
  const float* wsrc1 = W + (size_t)(n0 + (f1 & 3) * 16 + qr) * DK + kb +
                       (f1 >> 2) * 32 + quad * 8;
  const unsigned wdst0 = (unsigned)(f0 * 64 + lane) * 16;
  const unsigned wdst1 = wdst0 + 1024;

  // a-frag stream base: chunk (K64*32 + si*16 + g)*64 + lane, K64 = kz*32 + ...
  const bf16x8* ap = (const bf16x8*)xb + ((size_t)(kz * 32) * 32) * 64 + lane;

  f32x4v acc[2][4];
#pragma unroll
  for (int a = 0; a < 2; ++a)
#pragma unroll
    for (int b = 0; b < 4; ++b) acc[a][b] = (f32x4v){0.f, 0.f, 0.f, 0.f};

  // prologue: W(0) -> g[0] -> wsm[0];  W(1) -> g[1] (packed at it=0).
  float4 g[2][4];
  g[0][0] = *(const float4*)(wsrc0);
  g[0][1] = *(const float4*)(wsrc0 + 4);
  g[0][2] = *(const float4*)(wsrc1);
  g[0][3] = *(const float4*)(wsrc1 + 4);
  g[1][0] = *(const float4*)(wsrc0 + BK);
  g[1][1] = *(const float4*)(wsrc0 + BK + 4);
  g[1][2] = *(const float4*)(wsrc1 + BK);
  g[1][3] = *(const float4*)(wsrc1 + BK + 4);
  *(bf16x8*)((char*)wsm[0] + wdst0) = pack8(g[0][0], g[0][1]);
  *(bf16x8*)((char*)wsm[0] + wdst1) = pack8(g[0][2], g[0][3]);
  __syncthreads();

#pragma unroll 2
  for (int it = 0; it < NITER; ++it) {
    const char* wcur = (const char*)wsm[it & 1];
    // (1) av for k-slices s=0,1 (K64 = it*2): 4 coalesced 16B L2 loads
    bf16x8 av[2][2];
#pragma unroll
    for (int si = 0; si < 2; ++si)
#pragma unroll
      for (int mt = 0; mt < 2; ++mt)
        av[si][mt] =
            ap[(size_t)((it * 2) * 32 + si * 16 + w * 2 + mt) * 64];
    // (2) MFMA s=0,1 (b-frags: linear lane*16 ds_read_b128, conflict-free)
#pragma unroll
    for (int s = 0; s < 2; ++s) {
      bf16x8 b[4];
#pragma unroll
      for (int sub = 0; sub < 4; ++sub)
        b[sub] = *(const bf16x8*)(wcur + (((s * 4 + sub) * 64 + lane) * 16));
#pragma unroll
      for (int mt = 0; mt < 2; ++mt)
#pragma unroll
        for (int sub = 0; sub < 4; ++sub)
          acc[mt][sub] = __builtin_amdgcn_mfma_f32_16x16x32_bf16(
              av[s][mt], b[sub], acc[mt][sub], 0, 0, 0);
    }
    // (3) av for k-slices s=2,3 (K64 = it*2+1) -- BEFORE the W issue so the
    // MFMA vmcnt wait never chains behind the fresh HBM loads (in-order).
#pragma unroll
    for (int si = 0; si < 2; ++si)
#pragma unroll
      for (int mt = 0; mt < 2; ++mt)
        av[si][mt] =
            ap[(size_t)((it * 2 + 1) * 32 + si * 16 + w * 2 + mt) * 64];
    // (4) issue W(it+2) into g[it&1] (W(it) in there was packed at it-1)
    if (it + 2 < NITER) {
      const float* p0 = wsrc0 + (size_t)(it + 2) * BK;
      const float* p1 = wsrc1 + (size_t)(it + 2) * BK;
      g[it & 1][0] = *(const float4*)(p0);
      g[it & 1][1] = *(const float4*)(p0 + 4);
      g[it & 1][2] = *(const float4*)(p1);
      g[it & 1][3] = *(const float4*)(p1 + 4);
    }
    // (5) MFMA s=2,3
#pragma unroll
    for (int s = 2; s < 4; ++s) {
      bf16x8 b[4];
#pragma unroll
      for (int sub = 0; sub < 4; ++sub)
        b[sub] = *(const bf16x8*)(wcur + (((s * 4 + sub) * 64 + lane) * 16));
#pragma unroll
      for (int mt = 0; mt < 2; ++mt)
#pragma unroll
        for (int sub = 0; sub < 4; ++sub)
          acc[mt][sub] = __builtin_amdgcn_mfma_f32_16x16x32_bf16(
              av[s - 2][mt], b[sub], acc[mt][sub], 0, 0, 0);
    }
    // (6) pack W(it+1) from g[(it+1)&1] -- loaded a full iteration ago, so
    // the vmcnt wait here is ~0: the barrier carries no HBM latency.
    if (it + 1 < NITER) {
      char* wnxt = (char*)wsm[(it + 1) & 1];
      *(bf16x8*)(wnxt + wdst0) = pack8(g[(it + 1) & 1][0], g[(it + 1) & 1][1]);
      *(bf16x8*)(wnxt + wdst1) = pack8(g[(it + 1) & 1][2], g[(it + 1) & 1][3]);
    }
    __syncthreads();
  }

  if (kz == 0) {  // LoRA tail: one K=32 MFMA round (cols >=16 zero).
                  // y built by summing the 8 per-ks partial slots.
    const float4 z = {0.f, 0.f, 0.f, 0.f};
    bf16x8 b[4];
#pragma unroll
    for (int sub = 0; sub < 4; ++sub) {
      const float* ap2 = Aw + (size_t)(n0 + sub * 16 + qr) * RLORA + quad * 8;
      float4 p0 = (quad < 2) ? *(const float4*)(ap2) : z;
      float4 p1 = (quad < 2) ? *(const float4*)(ap2 + 4) : z;
      b[sub] = pack8(p0, p1);
    }
#pragma unroll
    for (int mt = 0; mt < 2; ++mt) {
      float4 q0 = z, q1 = z;
      if (quad < 2) {
        const float* yp =
            y32p + (size_t)(w * 32 + mt * 16 + qr) * RLORA + quad * 8;
#pragma unroll
        for (int ks = 0; ks < 8; ++ks) {
          const float* sp = yp + (size_t)ks * (DM * RLORA);
          const float4 a0 = *(const float4*)(sp);
          const float4 a1 = *(const float4*)(sp + 4);
          q0.x += a0.x; q0.y += a0.y; q0.z += a0.z; q0.w += a0.w;
          q1.x += a1.x; q1.y += a1.y; q1.z += a1.z; q1.w += a1.w;
        }
      }
      bf16x8 avt = pack8(q0, q1);
#pragma unroll
      for (int sub = 0; sub < 4; ++sub)
        acc[mt][sub] = __builtin_amdgcn_mfma_f32_16x16x32_bf16(
            avt, b[sub], acc[mt][sub], 0, 0, 0);
    }
  }

  // epilogue: C/D col=lane&15 (n), row=quad*4+rg (m)  [m89-verified]
  if (part) {
    float* pb = part + (size_t)kz * DM * DN;
#pragma unroll
    for (int mt = 0; mt < 2; ++mt)
#pragma unroll
      for (int sub = 0; sub < 4; ++sub) {
        float* p = pb + (size_t)(w * 32 + mt * 16 + quad * 4) * DN +
                   n0 + sub * 16 + qr;
#pragma unroll
        for (int rg = 0; rg < 4; ++rg) p[(size_t)rg * DN] = acc[mt][sub][rg];
      }
  } else {
    float* ob = out;
#pragma unroll
    for (int mt = 0; mt < 2; ++mt)
#pragma unroll
      for (int sub = 0; sub < 4; ++sub) {
        float* p = ob + (size_t)(w * 32 + mt * 16 + quad * 4) * DN +
                   n0 + sub * 16 + qr;
#pragma unroll
        for (int rg = 0; rg < 4; ++rg)
          atomicAdd(p + (size_t)rg * DN, acc[mt][sub][rg]);
      }
  }
}

// out = sum_kz part[kz]  (fully overwrites out).  grid 2048 x 256.
__global__ __launch_bounds__(256) void reduce_k(
    const float* __restrict__ part, float* __restrict__ out) {
  size_t i = ((size_t)blockIdx.x * 256 + threadIdx.x) * 4;
  float4 s = *(const float4*)(part + i);
#pragma unroll
  for (int kzi = 1; kzi < KSPLIT; ++kzi) {
    float4 v = *(const float4*)(part + (size_t)kzi * DM * DN + i);
    s.x += v.x; s.y += v.y; s.z += v.z; s.w += v.w;
  }
  *(float4*)(out + i) = s;
}

// ---------------------------------------------------------------------------
extern "C" void kernel_launch(void* const* d_in, const int* in_sizes, int n_in,
                              void* d_out, int out_size, void* d_ws, size_t ws_size,
                              hipStream_t stream) {
  const float* x  = (const float*)d_in[0];   // [4,64,8192]
  const float* W  = (const float*)d_in[1];   // [8192,8192]
  const float* A  = (const float*)d_in[2];   // [8192,16]
  const float* Bm = (const float*)d_in[3];   // [16,8192]
  float* out = (float*)d_out;

  unsigned short* xb = (unsigned short*)d_ws;             // 4 MiB frag-linear
  float* y32p = (float*)((char*)d_ws + (4u << 20));       // 128 KiB partials
  size_t base_bytes = (4u << 20) + (size_t)8 * DM * RLORA * 4;
  size_t part_bytes = (size_t)KSPLIT * DM * DN * 4;       // 32 MiB
  bool use_part = ws_size >= base_bytes + part_bytes;
  float* part = use_part ? (float*)((char*)d_ws + base_bytes) : nullptr;

  if (!use_part)
    hipMemsetAsync(d_out, 0, (size_t)out_size * sizeof(float), stream);
  prep_x<<<dim3(8, 64), 256, 0, stream>>>(x, Bm, xb, y32p);
  lora_gemm<<<512, 512, 0, stream>>>(xb, W, y32p, A, out, part);
  if (use_part) reduce_k<<<2048, 256, 0, stream>>>(part, out);
}

// Round 6
// 417.970 us; speedup vs baseline: 1.5242x; 1.0112x over previous
//
#include <hip/hip_runtime.h>
#include <stdint.h>

// out[m,n] = sum_k x[m,k]*W[n,k] + sum_r y[m,r]*A[n,r],  y = x @ B^T
// M=256, N=8192, K=8192, R=16. fp32 in/out; bf16 MFMA compute (thr 0.18).
//
// R11: isolate R10's two changes after container failure. The raw-barrier
// counted-wait loop (hang suspect) is REVERTED to __syncthreads() (R9 form,
// known-good 422.7us). The bf16 part spill is KEPT: split-K partials stored
// bf16 (32->16 MiB write, 16 MiB read in reduce_k); partials O(1), bf16 rel
// 2^-9 -> absmax +~0.01 vs 0.18 thr.
// Carried: R9 prep_x LDS-transpose + y32p partials (no memset/atomics);
// R7 BK=128 2-deep W ping-pong; R6 8mx1n waves, kz<->XCD-pair affinity.

#define DM 256
#define DK 8192
#define DN 8192
#define RLORA 16

#define TN 64
#define BK 128
#define KSPLIT 4
#define KCHUNK (DK / KSPLIT)    // 2048
#define NITER (KCHUNK / BK)     // 16

typedef short bf16x8 __attribute__((ext_vector_type(8)));   // 4 VGPRs
typedef unsigned short u16x8 __attribute__((ext_vector_type(8)));
typedef float f32x4v __attribute__((ext_vector_type(4)));

__device__ __forceinline__ unsigned short f2bf(float f) {
  unsigned u = __builtin_bit_cast(unsigned, f);
  u += 0x7FFFu + ((u >> 16) & 1u);           // RNE
  return (unsigned short)(u >> 16);
}

__device__ __forceinline__ float bf2f(unsigned short h) {
  unsigned u = (unsigned)h << 16;
  return __builtin_bit_cast(float, u);
}

__device__ __forceinline__ bf16x8 pack8(float4 a, float4 b) {
  bf16x8 r;
  r[0] = (short)f2bf(a.x); r[1] = (short)f2bf(a.y);
  r[2] = (short)f2bf(a.z); r[3] = (short)f2bf(a.w);
  r[4] = (short)f2bf(b.x); r[5] = (short)f2bf(b.y);
  r[6] = (short)f2bf(b.z); r[7] = (short)f2bf(b.w);
  return r;
}

// ---------------------------------------------------------------------------
// prep_x: x -> bf16 in frag-linear chunk order, + partial y = x @ B^T.
// Chunk c = (K64*32 + s*16 + g)*64 + (oct*16 + r), 16 B, holding
// x[g*16+r][K64*64 + s*32 + oct*8 .. +8)  (A-operand layout: lane&15=m-row,
// lane>>4=k-octet).  grid (8, 64) x 256 thr.  Partial y sums go to
// y32p[ks][m][r] (written exactly once -> no memset, no atomics).
__global__ __launch_bounds__(256) void prep_x(
    const float* __restrict__ x, const float* __restrict__ Bm,
    unsigned short* __restrict__ xb, float* __restrict__ y32p) {
  const int ks = blockIdx.x;
  const int m0 = blockIdx.y * 4;
  const int t = threadIdx.x;
  const int k = ks * 1024 + t * 4;
  const int K64 = k >> 6, s = (k >> 5) & 1, oct = (k >> 3) & 3;
  const int e = k & 7;                       // 0 or 4
  float4 xv[4];
#pragma unroll
  for (int i = 0; i < 4; ++i) {
    const int m = m0 + i;
    const int g = m >> 4, r = m & 15;
    xv[i] = *(const float4*)(x + (size_t)m * DK + k);
    ushort4 h;
    h.x = f2bf(xv[i].x); h.y = f2bf(xv[i].y);
    h.z = f2bf(xv[i].z); h.w = f2bf(xv[i].w);
    const size_t chunk = (size_t)(K64 * 32 + s * 16 + g) * 64 + oct * 16 + r;
    *(ushort4*)(xb + chunk * 8 + e) = h;
  }
  float acc[4][RLORA];
#pragma unroll
  for (int r = 0; r < RLORA; ++r) {
    float4 b = *(const float4*)(Bm + (size_t)r * DK + k);
#pragma unroll
    for (int i = 0; i < 4; ++i)
      acc[i][r] = xv[i].x * b.x + xv[i].y * b.y + xv[i].z * b.z + xv[i].w * b.w;
  }
  // ---- reduction: 256 threads x 64 values -> 64 sums, via LDS transpose.
  // tr[t][(v+t)&63]: per store/load instruction bank index = (v+t)&63 is
  // distinct across 32 consecutive lanes -> conflict-free (2 lanes/bank).
  __shared__ float tr[256][64];
#pragma unroll
  for (int i = 0; i < 4; ++i)
#pragma unroll
    for (int r = 0; r < RLORA; ++r) {
      const int v = i * 16 + r;
      tr[t][(v + t) & 63] = acc[i][r];
    }
  __syncthreads();
  const int v = t & 63, q = t >> 6;          // value, row-quarter
  float sq = 0.f;
#pragma unroll
  for (int j = 0; j < 64; ++j)
    sq += tr[q * 64 + j][(v + j) & 63];      // (v + q*64 + j)&63 == (v+j)&63
  __syncthreads();
  ((float*)tr)[q * 64 + v] = sq;             // tr2[4][64]
  __syncthreads();
  if (t < 64) {
    float sum = ((float*)tr)[t] + ((float*)tr)[64 + t] +
                ((float*)tr)[128 + t] + ((float*)tr)[192 + t];
    // slot = ks*4096 + m*16 + r, written exactly once per launch
    y32p[(size_t)ks * (DM * RLORA) + (m0 + (t >> 4)) * RLORA + (t & 15)] = sum;
  }
}

// ---------------------------------------------------------------------------
// Main GEMM.  grid 512 x 1 (flat), 512 thr = 8 waves, wave w owns rows
// [w*32, w*32+32) x all TN=64 cols.  kz = XCD-pair (bid&7)>>1 so each XCD
// only touches its 1 MiB xb slice (L2-resident).
__global__ __launch_bounds__(512, 4) void lora_gemm(
    const unsigned short* __restrict__ xb,   // frag-linear bf16 x
    const float* __restrict__ W,             // [8192][8192] fp32
    const float* __restrict__ y32p,          // [8][256][16] fp32 partials
    const float* __restrict__ Aw,            // [8192][16] fp32
    float* __restrict__ out,                 // [256][8192] fp32
    unsigned short* __restrict__ part) {     // [KSPLIT][256][8192] bf16 | null
  __shared__ unsigned short wsm[2][8192];    // 2 x 16 KB bf16 W-tile (64n x 128k)

  const int tid = threadIdx.x;
  const int lane = tid & 63, w = tid >> 6;   // w = m-slice 0..7
  const int qr = lane & 15, quad = lane >> 4;

  // XCD-affine decode: xcd = bid&7 (round-robin dispatch), kz fixed per
  // XCD pair, nblk bijective over 0..127 for each kz.
  const int bid = blockIdx.x;
  const int xcd = bid & 7;
  const int kz = xcd >> 1;
  const int nblk = (bid >> 3) + ((xcd & 1) << 6);
  const int n0 = nblk * TN;
  const int kb = kz * KCHUNK;

  // W staging: thread stages frags f0=2w, f1=2w+1.  Frag f holds
  // W[n0 + (f&3)*16 + qr][kb + it*128 + (f>>2)*32 + quad*8 .. +8) as bf16x8
  // at LDS offset f*1024 + lane*16 (linear, conflict-free b128 writes).
  const int f0 = w * 2, f1 = f0 + 1;
  const float* wsrc0 = W + (size_t)(n0 + (f0 & 3) * 16 + qr) * DK + kb +
                       (f0 >> 2) * 32 + quad * 8;
  const float* wsrc1 = W + (size_t)(n0 + (f1 & 3) * 16 + qr) * DK + kb +
                       (f1 >> 2) * 32 + quad * 8;
  const unsigned wdst0 = (unsigned)(f0 * 64 + lane) * 16;
  const unsigned wdst1 = wdst0 + 1024;

  // a-frag stream base: chunk (K64*32 + si*16 + g)*64 + lane, K64 = kz*32 + ...
  const bf16x8* ap = (const bf16x8*)xb + ((size_t)(kz * 32) * 32) * 64 + lane;

  f32x4v acc[2][4];
#pragma unroll
  for (int a = 0; a < 2; ++a)
#pragma unroll
    for (int b = 0; b < 4; ++b) acc[a][b] = (f32x4v){0.f, 0.f, 0.f, 0.f};

  // prologue: W(0) -> g[0] -> wsm[0];  W(1) -> g[1] (packed at it=0).
  float4 g[2][4];
  g[0][0] = *(const float4*)(wsrc0);
  g[0][1] = *(const float4*)(wsrc0 + 4);
  g[0][2] = *(const float4*)(wsrc1);
  g[0][3] = *(const float4*)(wsrc1 + 4);
  g[1][0] = *(const float4*)(wsrc0 + BK);
  g[1][1] = *(const float4*)(wsrc0 + BK + 4);
  g[1][2] = *(const float4*)(wsrc1 + BK);
  g[1][3] = *(const float4*)(wsrc1 + BK + 4);
  *(bf16x8*)((char*)wsm[0] + wdst0) = pack8(g[0][0], g[0][1]);
  *(bf16x8*)((char*)wsm[0] + wdst1) = pack8(g[0][2], g[0][3]);
  __syncthreads();

#pragma unroll 2
  for (int it = 0; it < NITER; ++it) {
    const char* wcur = (const char*)wsm[it & 1];
    // (1) av for k-slices s=0,1 (K64 = it*2): 4 coalesced 16B L2 loads
    bf16x8 av[2][2];
#pragma unroll
    for (int si = 0; si < 2; ++si)
#pragma unroll
      for (int mt = 0; mt < 2; ++mt)
        av[si][mt] =
            ap[(size_t)((it * 2) * 32 + si * 16 + w * 2 + mt) * 64];
    // (2) MFMA s=0,1 (b-frags: linear lane*16 ds_read_b128, conflict-free)
#pragma unroll
    for (int s = 0; s < 2; ++s) {
      bf16x8 b[4];
#pragma unroll
      for (int sub = 0; sub < 4; ++sub)
        b[sub] = *(const bf16x8*)(wcur + (((s * 4 + sub) * 64 + lane) * 16));
#pragma unroll
      for (int mt = 0; mt < 2; ++mt)
#pragma unroll
        for (int sub = 0; sub < 4; ++sub)
          acc[mt][sub] = __builtin_amdgcn_mfma_f32_16x16x32_bf16(
              av[s][mt], b[sub], acc[mt][sub], 0, 0, 0);
    }
    // (3) av for k-slices s=2,3 (K64 = it*2+1) -- BEFORE the W issue so the
    // MFMA vmcnt wait never chains behind the fresh HBM loads (in-order).
#pragma unroll
    for (int si = 0; si < 2; ++si)
#pragma unroll
      for (int mt = 0; mt < 2; ++mt)
        av[si][mt] =
            ap[(size_t)((it * 2 + 1) * 32 + si * 16 + w * 2 + mt) * 64];
    // (4) issue W(it+2) into g[it&1] (W(it) in there was packed at it-1)
    if (it + 2 < NITER) {
      const float* p0 = wsrc0 + (size_t)(it + 2) * BK;
      const float* p1 = wsrc1 + (size_t)(it + 2) * BK;
      g[it & 1][0] = *(const float4*)(p0);
      g[it & 1][1] = *(const float4*)(p0 + 4);
      g[it & 1][2] = *(const float4*)(p1);
      g[it & 1][3] = *(const float4*)(p1 + 4);
    }
    // (5) MFMA s=2,3
#pragma unroll
    for (int s = 2; s < 4; ++s) {
      bf16x8 b[4];
#pragma unroll
      for (int sub = 0; sub < 4; ++sub)
        b[sub] = *(const bf16x8*)(wcur + (((s * 4 + sub) * 64 + lane) * 16));
#pragma unroll
      for (int mt = 0; mt < 2; ++mt)
#pragma unroll
        for (int sub = 0; sub < 4; ++sub)
          acc[mt][sub] = __builtin_amdgcn_mfma_f32_16x16x32_bf16(
              av[s - 2][mt], b[sub], acc[mt][sub], 0, 0, 0);
    }
    // (6) pack W(it+1) from g[(it+1)&1] -- loaded a full iteration ago, so
    // the vmcnt wait here is ~0: the barrier carries little HBM latency.
    if (it + 1 < NITER) {
      char* wnxt = (char*)wsm[(it + 1) & 1];
      *(bf16x8*)(wnxt + wdst0) = pack8(g[(it + 1) & 1][0], g[(it + 1) & 1][1]);
      *(bf16x8*)(wnxt + wdst1) = pack8(g[(it + 1) & 1][2], g[(it + 1) & 1][3]);
    }
    __syncthreads();
  }

  if (kz == 0) {  // LoRA tail: one K=32 MFMA round (cols >=16 zero).
                  // y built by summing the 8 per-ks partial slots.
    const float4 z = {0.f, 0.f, 0.f, 0.f};
    bf16x8 b[4];
#pragma unroll
    for (int sub = 0; sub < 4; ++sub) {
      const float* ap2 = Aw + (size_t)(n0 + sub * 16 + qr) * RLORA + quad * 8;
      float4 p0 = (quad < 2) ? *(const float4*)(ap2) : z;
      float4 p1 = (quad < 2) ? *(const float4*)(ap2 + 4) : z;
      b[sub] = pack8(p0, p1);
    }
#pragma unroll
    for (int mt = 0; mt < 2; ++mt) {
      float4 q0 = z, q1 = z;
      if (quad < 2) {
        const float* yp =
            y32p + (size_t)(w * 32 + mt * 16 + qr) * RLORA + quad * 8;
#pragma unroll
        for (int ks = 0; ks < 8; ++ks) {
          const float* sp = yp + (size_t)ks * (DM * RLORA);
          const float4 a0 = *(const float4*)(sp);
          const float4 a1 = *(const float4*)(sp + 4);
          q0.x += a0.x; q0.y += a0.y; q0.z += a0.z; q0.w += a0.w;
          q1.x += a1.x; q1.y += a1.y; q1.z += a1.z; q1.w += a1.w;
        }
      }
      bf16x8 avt = pack8(q0, q1);
#pragma unroll
      for (int sub = 0; sub < 4; ++sub)
        acc[mt][sub] = __builtin_amdgcn_mfma_f32_16x16x32_bf16(
            avt, b[sub], acc[mt][sub], 0, 0, 0);
    }
  }

  // epilogue: C/D col=lane&15 (n), row=quad*4+rg (m)  [m89-verified]
  if (part) {
    unsigned short* pb = part + (size_t)kz * DM * DN;
#pragma unroll
    for (int mt = 0; mt < 2; ++mt)
#pragma unroll
      for (int sub = 0; sub < 4; ++sub) {
        unsigned short* p = pb + (size_t)(w * 32 + mt * 16 + quad * 4) * DN +
                            n0 + sub * 16 + qr;
#pragma unroll
        for (int rg = 0; rg < 4; ++rg)
          p[(size_t)rg * DN] = f2bf(acc[mt][sub][rg]);
      }
  } else {
    float* ob = out;
#pragma unroll
    for (int mt = 0; mt < 2; ++mt)
#pragma unroll
      for (int sub = 0; sub < 4; ++sub) {
        float* p = ob + (size_t)(w * 32 + mt * 16 + quad * 4) * DN +
                   n0 + sub * 16 + qr;
#pragma unroll
        for (int rg = 0; rg < 4; ++rg)
          atomicAdd(p + (size_t)rg * DN, acc[mt][sub][rg]);
      }
  }
}

// out = sum_kz part[kz] (bf16 partials, fp32 accumulate).  grid 1024 x 256.
__global__ __launch_bounds__(256) void reduce_k(
    const unsigned short* __restrict__ part, float* __restrict__ out) {
  size_t i = ((size_t)blockIdx.x * 256 + threadIdx.x) * 8;
  float s[8] = {0.f, 0.f, 0.f, 0.f, 0.f, 0.f, 0.f, 0.f};
#pragma unroll
  for (int kzi = 0; kzi < KSPLIT; ++kzi) {
    u16x8 v = *(const u16x8*)(part + (size_t)kzi * DM * DN + i);
#pragma unroll
    for (int e = 0; e < 8; ++e) s[e] += bf2f(v[e]);
  }
  float4 o0 = {s[0], s[1], s[2], s[3]};
  float4 o1 = {s[4], s[5], s[6], s[7]};
  *(float4*)(out + i) = o0;
  *(float4*)(out + i + 4) = o1;
}

// ---------------------------------------------------------------------------
extern "C" void kernel_launch(void* const* d_in, const int* in_sizes, int n_in,
                              void* d_out, int out_size, void* d_ws, size_t ws_size,
                              hipStream_t stream) {
  const float* x  = (const float*)d_in[0];   // [4,64,8192]
  const float* W  = (const float*)d_in[1];   // [8192,8192]
  const float* A  = (const float*)d_in[2];   // [8192,16]
  const float* Bm = (const float*)d_in[3];   // [16,8192]
  float* out = (float*)d_out;

  unsigned short* xb = (unsigned short*)d_ws;             // 4 MiB frag-linear
  float* y32p = (float*)((char*)d_ws + (4u << 20));       // 128 KiB partials
  size_t base_bytes = (4u << 20) + (size_t)8 * DM * RLORA * 4;
  size_t part_bytes = (size_t)KSPLIT * DM * DN * 2;       // 16 MiB bf16
  bool use_part = ws_size >= base_bytes + part_bytes;
  unsigned short* part =
      use_part ? (unsigned short*)((char*)d_ws + base_bytes) : nullptr;

  if (!use_part)
    hipMemsetAsync(d_out, 0, (size_t)out_size * sizeof(float), stream);
  prep_x<<<dim3(8, 64), 256, 0, stream>>>(x, Bm, xb, y32p);
  lora_gemm<<<512, 512, 0, stream>>>(xb, W, y32p, A, out, part);
  if (use_part) reduce_k<<<1024, 256, 0, stream>>>(part, out);
}